// Round 7
// baseline (351.528 us; speedup 1.0000x reference)
//
#include <hip/hip_runtime.h>
#include <hip/hip_fp16.h>

#define N_ 4
#define H_ 256
#define W_ 256
#define C_ 96
#define CH 48      // channels per unit (half of C_)
#define NFR 12     // wpass scan fragments per thread = CH/4
#define HFR 6      // hpass fragments per thread (512-thr blocks) = 24/4
#define TP 258     // tile row stride (halves)
#define SP 132     // stage row stride (floats)
#define NFILT 4

__constant__ float c_a[NFILT] = {0.1f, 0.3f, 0.4f, 0.8f};

// Forward scan, 256 positions as lane*4+j. Truncated Kogge-Stone: carry
// multiplier A=a^4<=0.41; omitted terms weigh A^16~6e-7 -> steps {1,2,4,8}.
__device__ __forceinline__ void scan_fwd(float &v0, float &v1, float &v2, float &v3,
                                         float a, int lane) {
  const float b = 1.0f - a;
  const float a2 = a * a, a3 = a2 * a, a4 = a2 * a2;
  float t0 = b * v0;
  float t1 = fmaf(a, t0, b * v1);
  float t2 = fmaf(a, t1, b * v2);
  float t3 = fmaf(a, t2, b * v3);
  if (lane == 0) {  // init carry y_{-1} := x_0  => y_0 = x_0
    t0 = fmaf(a,  v0, t0);
    t1 = fmaf(a2, v0, t1);
    t2 = fmaf(a3, v0, t2);
    t3 = fmaf(a4, v0, t3);
  }
  float c = t3;
  float m = a4;
  #pragma unroll
  for (int d = 1; d <= 8; d <<= 1) {
    float o = __shfl_up(c, (unsigned)d, 64);
    if (lane >= d) c = fmaf(m, o, c);
    m = m * m;
  }
  float cin = __shfl_up(c, 1u, 64);
  if (lane == 0) cin = 0.0f;
  v0 = fmaf(a,  cin, t0);
  v1 = fmaf(a2, cin, t1);
  v2 = fmaf(a3, cin, t2);
  v3 = fmaf(a4, cin, t3);
}

__device__ __forceinline__ void scan_bwd(float &v0, float &v1, float &v2, float &v3,
                                         float a, int lane) {
  const float b = 1.0f - a;
  const float a2 = a * a, a3 = a2 * a, a4 = a2 * a2;
  float t3 = b * v3;
  float t2 = fmaf(a, t3, b * v2);
  float t1 = fmaf(a, t2, b * v1);
  float t0 = fmaf(a, t1, b * v0);
  if (lane == 63) {  // init carry := y_255
    t3 = fmaf(a,  v3, t3);
    t2 = fmaf(a2, v3, t2);
    t1 = fmaf(a3, v3, t1);
    t0 = fmaf(a4, v3, t0);
  }
  float c = t0;
  float m = a4;
  #pragma unroll
  for (int d = 1; d <= 8; d <<= 1) {
    float o = __shfl_down(c, (unsigned)d, 64);
    if (lane < 64 - d) c = fmaf(m, o, c);
    m = m * m;
  }
  float cin = __shfl_down(c, 1u, 64);
  if (lane == 63) cin = 0.0f;
  v3 = fmaf(a,  cin, t3);
  v2 = fmaf(a2, cin, t2);
  v1 = fmaf(a3, cin, t1);
  v0 = fmaf(a4, cin, t0);
}

// W-pass, nf==4 path (round-6 winner, UNCHANGED): 1D grid of 8192.
//   bid&7  = chalf + 2*n        (XCD digit: no fi, no h)
//   bid>>3 = fi + 4*h           (fi fastest)
// => fi-siblings same XCD, near-concurrent -> x fetched ~once (FETCH 66MB);
// => h-adjacent same-unit blocks same XCD -> 96B segments merge (amp 1.04).
__global__ __launch_bounds__(256, 4)
void k_wpass4(const float* __restrict__ x, __half* __restrict__ inter) {
  __shared__ __half tile[CH * TP];
  const int bid = blockIdx.x;
  const int d = bid & 7, r = bid >> 3;
  const int chalf = d & 1;
  const int n     = d >> 1;
  const int fi    = r & 3;
  const int h     = r >> 2;
  const int row   = n * H_ + h;
  const int c0    = chalf * CH;
  const float a   = c_a[fi];
  const int t     = threadIdx.x;
  const int wave  = t >> 6, lane = t & 63;

  const float* xrow = x + (size_t)row * (W_ * C_) + c0;
  #pragma unroll
  for (int i = 0; i < 12; ++i) {
    int idx = t + i * 256;
    int w = idx / 12, c4 = idx % 12;
    const float4 v = *(const float4*)(xrow + (size_t)w * C_ + 4 * c4);
    tile[(4 * c4 + 0) * TP + w] = __float2half(v.x);
    tile[(4 * c4 + 1) * TP + w] = __float2half(v.y);
    tile[(4 * c4 + 2) * TP + w] = __float2half(v.z);
    tile[(4 * c4 + 3) * TP + w] = __float2half(v.w);
  }
  __syncthreads();
  #pragma unroll
  for (int ci = 0; ci < NFR; ++ci) {
    const int c = wave + 4 * ci;
    __half2* p = (__half2*)(tile + c * TP + 4 * lane);
    float2 f01 = __half22float2(p[0]);
    float2 f23 = __half22float2(p[1]);
    float v0 = f01.x, v1 = f01.y, v2 = f23.x, v3 = f23.y;
    scan_fwd(v0, v1, v2, v3, a, lane);
    scan_bwd(v0, v1, v2, v3, a, lane);
    p[0] = __floats2half2_rn(v0, v1);
    p[1] = __floats2half2_rn(v2, v3);
  }
  __syncthreads();
  // inter[((fi*2+chalf)*N + n)*W + w]: contiguous H*CH-halves chunk per w.
  __half* ibase = inter + (((size_t)(fi * 2 + chalf) * N_ * W_ + (size_t)n * W_)
                           * (H_ * CH)) + (size_t)h * CH;
  #pragma unroll
  for (int i = 0; i < 6; ++i) {
    int idx = t + i * 256;               // 1536 uint4s
    int w = idx / 6, j = idx % 6;
    union { uint4 u4; ushort sv[8]; } pk;
    #pragma unroll
    for (int k = 0; k < 8; ++k)
      pk.sv[k] = __half_as_ushort(tile[(8 * j + k) * TP + w]);
    *(uint4*)(ibase + (size_t)w * (H_ * CH) + 8 * j) = pk.u4;
  }
}

// W-pass, generic fallback (round-0 verbatim, 2D grid) for nf<4.
__global__ __launch_bounds__(256, 4)
void k_wpass(const float* __restrict__ x, __half* __restrict__ inter,
             int f_start, int nf) {
  __shared__ __half tile[CH * TP];
  const int chalf = blockIdx.x & 1;
  const int fi    = blockIdx.x >> 1;
  const int row   = blockIdx.y;
  const int h     = row & 255;
  const int c0    = chalf * CH;
  const float a   = c_a[f_start + fi];
  const int t     = threadIdx.x;
  const int wave  = t >> 6, lane = t & 63;

  const float* xrow = x + (size_t)row * (W_ * C_) + c0;
  #pragma unroll
  for (int i = 0; i < 12; ++i) {
    int idx = t + i * 256;
    int w = idx / 12, c4 = idx % 12;
    const float4 v = *(const float4*)(xrow + (size_t)w * C_ + 4 * c4);
    tile[(4 * c4 + 0) * TP + w] = __float2half(v.x);
    tile[(4 * c4 + 1) * TP + w] = __float2half(v.y);
    tile[(4 * c4 + 2) * TP + w] = __float2half(v.z);
    tile[(4 * c4 + 3) * TP + w] = __float2half(v.w);
  }
  __syncthreads();
  #pragma unroll
  for (int ci = 0; ci < NFR; ++ci) {
    const int c = wave + 4 * ci;
    __half2* p = (__half2*)(tile + c * TP + 4 * lane);
    float2 f01 = __half22float2(p[0]);
    float2 f23 = __half22float2(p[1]);
    float v0 = f01.x, v1 = f01.y, v2 = f23.x, v3 = f23.y;
    scan_fwd(v0, v1, v2, v3, a, lane);
    scan_bwd(v0, v1, v2, v3, a, lane);
    p[0] = __floats2half2_rn(v0, v1);
    p[1] = __floats2half2_rn(v2, v3);
  }
  __syncthreads();
  __half* ibase = inter + (((size_t)(fi * 2 + chalf) * N_ * W_ + (size_t)(row >> 8) * W_)
                           * (H_ * CH)) + (size_t)(row & 255) * CH;
  #pragma unroll
  for (int i = 0; i < 6; ++i) {
    int idx = t + i * 256;
    int w = idx / 6, j = idx % 6;
    union { uint4 u4; ushort sv[8]; } pk;
    #pragma unroll
    for (int k = 0; k < 8; ++k)
      pk.sv[k] = __half_as_ushort(tile[(8 * j + k) * TP + w]);
    *(uint4*)(ibase + (size_t)w * (H_ * CH) + 8 * j) = pk.u4;
  }
}

// H-pass, 512-thread blocks: waves 0-3 own channels 0-23, waves 4-7 own
// 24-47 of this block's chalf. Per-thread state halves (acc 24 + pf 12
// VGPR, forced <=64 via launch_bounds -> 8 waves/SIMD -> 4 blocks x 8
// waves = 32 waves/CU, vs ~100 VGPR/4 blocks/50% before). 1D grid 2048,
// XCD digit = chalf+2n matches the wpass writer XCD for residual L2 hits.
__global__ __launch_bounds__(512, 8)
void k_hpass(const __half* __restrict__ inter, const float* __restrict__ gate,
             float* __restrict__ out, int f_start, int nf, int accumulate) {
  __shared__ __align__(16) unsigned char smem[CH * SP * 4];  // 25344 B
  __half* tile = (__half*)smem;        // CH*TP*2 = 24768 B
  float*  stage = (float*)smem;        // CH*SP*4 (aliased, after scans)
  __shared__ float wlds[NFILT * CH];
  const int bid = blockIdx.x;
  const int d = bid & 7;
  const int chalf = d & 1;
  const int n     = d >> 1;
  const int w     = bid >> 3;
  const int c0 = chalf * CH;
  const int t = threadIdx.x;
  const int wave = t >> 6, lane = t & 63;
  const int whalf = wave >> 2, wsub = wave & 3;  // channel-half, sub-wave

  if (t < CH) {
    const int c = c0 + t;
    float g0 = gate[0 * C_ + c], g1 = gate[1 * C_ + c];
    float g2 = gate[2 * C_ + c], g3 = gate[3 * C_ + c];
    float mx = fmaxf(fmaxf(g0, g1), fmaxf(g2, g3));
    float e0 = __expf(g0 - mx), e1 = __expf(g1 - mx);
    float e2 = __expf(g2 - mx), e3 = __expf(g3 - mx);
    float inv = 1.0f / (e0 + e1 + e2 + e3);
    wlds[0 * CH + t] = e0 * inv;
    wlds[1 * CH + t] = e1 * inv;
    wlds[2 * CH + t] = e2 * inv;
    wlds[3 * CH + t] = e3 * inv;
  }

  float acc[HFR][4];
  #pragma unroll
  for (int ci = 0; ci < HFR; ++ci)
    acc[ci][0] = acc[ci][1] = acc[ci][2] = acc[ci][3] = 0.0f;

  const size_t chunk = (size_t)H_ * CH;  // halves per (fi,chalf,n,w) chunk
  uint4 pf[3];
  {
    const uint4* src = (const uint4*)(inter +
        ((size_t)(0 * 2 + chalf) * N_ * W_ + (size_t)n * W_ + w) * chunk);
    #pragma unroll
    for (int i = 0; i < 3; ++i) pf[i] = src[i * 512 + t];
  }

  for (int fi = 0; fi < nf; ++fi) {
    __syncthreads();                     // prev scan/stage reads done
    #pragma unroll
    for (int i = 0; i < 3; ++i) {
      int e = i * 512 + t;               // 1536 uint4s
      int hh = e / 6, c8 = e % 6;
      union { uint4 u4; ushort sv[8]; } pk;
      pk.u4 = pf[i];
      #pragma unroll
      for (int k = 0; k < 8; ++k)
        tile[(8 * c8 + k) * TP + hh] = __ushort_as_half(pk.sv[k]);
    }
    __syncthreads();
    if (fi + 1 < nf) {                   // prefetch next filter's chunk
      const uint4* src = (const uint4*)(inter +
          ((size_t)((fi + 1) * 2 + chalf) * N_ * W_ + (size_t)n * W_ + w) * chunk);
      #pragma unroll
      for (int i = 0; i < 3; ++i) pf[i] = src[i * 512 + t];
    }
    const float a = c_a[f_start + fi];
    #pragma unroll
    for (int ci = 0; ci < HFR; ++ci) {
      const int c = wsub + 4 * ci + 24 * whalf;
      const __half2* p = (const __half2*)(tile + c * TP + 4 * lane);
      float2 f01 = __half22float2(p[0]);
      float2 f23 = __half22float2(p[1]);
      float v0 = f01.x, v1 = f01.y, v2 = f23.x, v3 = f23.y;
      scan_fwd(v0, v1, v2, v3, a, lane);
      scan_bwd(v0, v1, v2, v3, a, lane);
      const float wg = wlds[(f_start + fi) * CH + c];
      acc[ci][0] = fmaf(wg, v0, acc[ci][0]);
      acc[ci][1] = fmaf(wg, v1, acc[ci][1]);
      acc[ci][2] = fmaf(wg, v2, acc[ci][2]);
      acc[ci][3] = fmaf(wg, v3, acc[ci][3]);
    }
  }

  // Output: two half-h rounds through the fp32 stage (aliases tile).
  #pragma unroll
  for (int r = 0; r < 2; ++r) {
    __syncthreads();
    if ((lane >> 5) == r) {
      const int hl = 4 * (lane & 31);
      #pragma unroll
      for (int ci = 0; ci < HFR; ++ci) {
        const int c = wsub + 4 * ci + 24 * whalf;
        float4* sp = (float4*)(stage + c * SP + hl);
        *sp = make_float4(acc[ci][0], acc[ci][1], acc[ci][2], acc[ci][3]);
      }
    }
    __syncthreads();
    float* obase = out + (((size_t)n * H_ + 128 * r) * W_ + w) * C_ + c0;
    #pragma unroll
    for (int i = 0; i < 3; ++i) {
      int idx = t + i * 512;             // 1536 float4s per round
      int hl = idx / 12, c4 = idx % 12;
      float4 v;
      v.x = stage[(4 * c4 + 0) * SP + hl];
      v.y = stage[(4 * c4 + 1) * SP + hl];
      v.z = stage[(4 * c4 + 2) * SP + hl];
      v.w = stage[(4 * c4 + 3) * SP + hl];
      float4* dst = (float4*)(obase + (size_t)hl * (W_ * C_) + 4 * c4);
      if (accumulate) {
        float4 pv = *dst;
        v.x += pv.x; v.y += pv.y; v.z += pv.z; v.w += pv.w;
      }
      *dst = v;
    }
  }
}

extern "C" void kernel_launch(void* const* d_in, const int* in_sizes, int n_in,
                              void* d_out, int out_size, void* d_ws, size_t ws_size,
                              hipStream_t stream) {
  const float* x    = (const float*)d_in[0];
  const float* gate = (const float*)d_in[1];
  float* out        = (float*)d_out;
  __half* inter     = (__half*)d_ws;

  const size_t per_f = (size_t)N_ * H_ * W_ * C_ * sizeof(__half);  // 50.3 MB
  int batch = 1;
  if (ws_size >= 4 * per_f)      batch = 4;
  else if (ws_size >= 2 * per_f) batch = 2;

  int done = 0;
  while (done < NFILT) {
    int nf = NFILT - done;
    if (nf > batch) nf = batch;
    if (nf == 4) {
      k_wpass4<<<dim3(8192), dim3(256), 0, stream>>>(x, inter);
    } else {
      dim3 g1(2 * nf, N_ * H_);
      k_wpass<<<g1, dim3(256), 0, stream>>>(x, inter, done, nf);
    }
    k_hpass<<<dim3(2048), dim3(512), 0, stream>>>(inter, gate, out, done, nf,
                                                  done > 0 ? 1 : 0);
    done += nf;
  }
}

// Round 8
// 315.296 us; speedup vs baseline: 1.1149x; 1.1149x over previous
//
#include <hip/hip_runtime.h>
#include <hip/hip_fp16.h>

#define N_ 4
#define H_ 256
#define W_ 256
#define C_ 96
#define CH 48      // channels per unit (half of C_)
#define NFR 12     // scan fragments per thread = CH/4
#define TP 258     // tile row stride (halves)
#define SP 132     // stage row stride (floats)
#define NFILT 4

__constant__ float c_a[NFILT] = {0.1f, 0.3f, 0.4f, 0.8f};

// Forward scan, 256 positions as lane*4+j. Truncated Kogge-Stone: carry
// multiplier A=a^4<=0.41; omitted terms weigh A^16~6e-7 -> steps {1,2,4,8}.
__device__ __forceinline__ void scan_fwd(float &v0, float &v1, float &v2, float &v3,
                                         float a, int lane) {
  const float b = 1.0f - a;
  const float a2 = a * a, a3 = a2 * a, a4 = a2 * a2;
  float t0 = b * v0;
  float t1 = fmaf(a, t0, b * v1);
  float t2 = fmaf(a, t1, b * v2);
  float t3 = fmaf(a, t2, b * v3);
  if (lane == 0) {  // init carry y_{-1} := x_0  => y_0 = x_0
    t0 = fmaf(a,  v0, t0);
    t1 = fmaf(a2, v0, t1);
    t2 = fmaf(a3, v0, t2);
    t3 = fmaf(a4, v0, t3);
  }
  float c = t3;
  float m = a4;
  #pragma unroll
  for (int d = 1; d <= 8; d <<= 1) {
    float o = __shfl_up(c, (unsigned)d, 64);
    if (lane >= d) c = fmaf(m, o, c);
    m = m * m;
  }
  float cin = __shfl_up(c, 1u, 64);
  if (lane == 0) cin = 0.0f;
  v0 = fmaf(a,  cin, t0);
  v1 = fmaf(a2, cin, t1);
  v2 = fmaf(a3, cin, t2);
  v3 = fmaf(a4, cin, t3);
}

__device__ __forceinline__ void scan_bwd(float &v0, float &v1, float &v2, float &v3,
                                         float a, int lane) {
  const float b = 1.0f - a;
  const float a2 = a * a, a3 = a2 * a, a4 = a2 * a2;
  float t3 = b * v3;
  float t2 = fmaf(a, t3, b * v2);
  float t1 = fmaf(a, t2, b * v1);
  float t0 = fmaf(a, t1, b * v0);
  if (lane == 63) {  // init carry := y_255
    t3 = fmaf(a,  v3, t3);
    t2 = fmaf(a2, v3, t2);
    t1 = fmaf(a3, v3, t1);
    t0 = fmaf(a4, v3, t0);
  }
  float c = t0;
  float m = a4;
  #pragma unroll
  for (int d = 1; d <= 8; d <<= 1) {
    float o = __shfl_down(c, (unsigned)d, 64);
    if (lane < 64 - d) c = fmaf(m, o, c);
    m = m * m;
  }
  float cin = __shfl_down(c, 1u, 64);
  if (lane == 63) cin = 0.0f;
  v3 = fmaf(a,  cin, t3);
  v2 = fmaf(a2, cin, t2);
  v1 = fmaf(a3, cin, t1);
  v0 = fmaf(a4, cin, t0);
}

// W-pass, nf==4 path (round-6 winner, UNCHANGED): 1D grid of 8192.
//   bid&7  = chalf + 2*n        (XCD digit: no fi, no h)
//   bid>>3 = fi + 4*h           (fi fastest)
// => fi-siblings same XCD, near-concurrent -> x fetched ~once (FETCH 66MB);
// => h-adjacent same-unit blocks same XCD -> 96B segments merge (amp 1.04).
__global__ __launch_bounds__(256, 4)
void k_wpass4(const float* __restrict__ x, __half* __restrict__ inter) {
  __shared__ __half tile[CH * TP];
  const int bid = blockIdx.x;
  const int d = bid & 7, r = bid >> 3;
  const int chalf = d & 1;
  const int n     = d >> 1;
  const int fi    = r & 3;
  const int h     = r >> 2;
  const int row   = n * H_ + h;
  const int c0    = chalf * CH;
  const float a   = c_a[fi];
  const int t     = threadIdx.x;
  const int wave  = t >> 6, lane = t & 63;

  const float* xrow = x + (size_t)row * (W_ * C_) + c0;
  #pragma unroll
  for (int i = 0; i < 12; ++i) {
    int idx = t + i * 256;
    int w = idx / 12, c4 = idx % 12;
    const float4 v = *(const float4*)(xrow + (size_t)w * C_ + 4 * c4);
    tile[(4 * c4 + 0) * TP + w] = __float2half(v.x);
    tile[(4 * c4 + 1) * TP + w] = __float2half(v.y);
    tile[(4 * c4 + 2) * TP + w] = __float2half(v.z);
    tile[(4 * c4 + 3) * TP + w] = __float2half(v.w);
  }
  __syncthreads();
  #pragma unroll
  for (int ci = 0; ci < NFR; ++ci) {
    const int c = wave + 4 * ci;
    __half2* p = (__half2*)(tile + c * TP + 4 * lane);
    float2 f01 = __half22float2(p[0]);
    float2 f23 = __half22float2(p[1]);
    float v0 = f01.x, v1 = f01.y, v2 = f23.x, v3 = f23.y;
    scan_fwd(v0, v1, v2, v3, a, lane);
    scan_bwd(v0, v1, v2, v3, a, lane);
    p[0] = __floats2half2_rn(v0, v1);
    p[1] = __floats2half2_rn(v2, v3);
  }
  __syncthreads();
  // inter[((fi*2+chalf)*N + n)*W + w]: contiguous H*CH-halves chunk per w.
  __half* ibase = inter + (((size_t)(fi * 2 + chalf) * N_ * W_ + (size_t)n * W_)
                           * (H_ * CH)) + (size_t)h * CH;
  #pragma unroll
  for (int i = 0; i < 6; ++i) {
    int idx = t + i * 256;               // 1536 uint4s
    int w = idx / 6, j = idx % 6;
    union { uint4 u4; ushort sv[8]; } pk;
    #pragma unroll
    for (int k = 0; k < 8; ++k)
      pk.sv[k] = __half_as_ushort(tile[(8 * j + k) * TP + w]);
    *(uint4*)(ibase + (size_t)w * (H_ * CH) + 8 * j) = pk.u4;
  }
}

// W-pass, generic fallback (round-0 verbatim, 2D grid) for nf<4.
__global__ __launch_bounds__(256, 4)
void k_wpass(const float* __restrict__ x, __half* __restrict__ inter,
             int f_start, int nf) {
  __shared__ __half tile[CH * TP];
  const int chalf = blockIdx.x & 1;
  const int fi    = blockIdx.x >> 1;
  const int row   = blockIdx.y;
  const int h     = row & 255;
  const int c0    = chalf * CH;
  const float a   = c_a[f_start + fi];
  const int t     = threadIdx.x;
  const int wave  = t >> 6, lane = t & 63;

  const float* xrow = x + (size_t)row * (W_ * C_) + c0;
  #pragma unroll
  for (int i = 0; i < 12; ++i) {
    int idx = t + i * 256;
    int w = idx / 12, c4 = idx % 12;
    const float4 v = *(const float4*)(xrow + (size_t)w * C_ + 4 * c4);
    tile[(4 * c4 + 0) * TP + w] = __float2half(v.x);
    tile[(4 * c4 + 1) * TP + w] = __float2half(v.y);
    tile[(4 * c4 + 2) * TP + w] = __float2half(v.z);
    tile[(4 * c4 + 3) * TP + w] = __float2half(v.w);
  }
  __syncthreads();
  #pragma unroll
  for (int ci = 0; ci < NFR; ++ci) {
    const int c = wave + 4 * ci;
    __half2* p = (__half2*)(tile + c * TP + 4 * lane);
    float2 f01 = __half22float2(p[0]);
    float2 f23 = __half22float2(p[1]);
    float v0 = f01.x, v1 = f01.y, v2 = f23.x, v3 = f23.y;
    scan_fwd(v0, v1, v2, v3, a, lane);
    scan_bwd(v0, v1, v2, v3, a, lane);
    p[0] = __floats2half2_rn(v0, v1);
    p[1] = __floats2half2_rn(v2, v3);
  }
  __syncthreads();
  __half* ibase = inter + (((size_t)(fi * 2 + chalf) * N_ * W_ + (size_t)(row >> 8) * W_)
                           * (H_ * CH)) + (size_t)(row & 255) * CH;
  #pragma unroll
  for (int i = 0; i < 6; ++i) {
    int idx = t + i * 256;
    int w = idx / 6, j = idx % 6;
    union { uint4 u4; ushort sv[8]; } pk;
    #pragma unroll
    for (int k = 0; k < 8; ++k)
      pk.sv[k] = __half_as_ushort(tile[(8 * j + k) * TP + w]);
    *(uint4*)(ibase + (size_t)w * (H_ * CH) + 8 * j) = pk.u4;
  }
}

// H-pass (round-6 verbatim, known-good ~85us): block = (chalf) x (n*W+w),
// 256 threads, 4 blocks/CU. Per filter: contiguous 24KB chunk -> 6 uint4
// regs (prefetched across filters, needs the ~100-VGPR budget of
// launch_bounds(256,4) — do NOT tighten: (512,8) forced 32 VGPR and
// regressed 85->124us in round 7) -> LDS transpose [c][h] -> scan +
// weighted accumulate -> staged coalesced out writes.
__global__ __launch_bounds__(256, 4)
void k_hpass(const __half* __restrict__ inter, const float* __restrict__ gate,
             float* __restrict__ out, int f_start, int nf, int accumulate) {
  __shared__ __align__(16) unsigned char smem[CH * SP * 4];  // 25344 B
  __half* tile = (__half*)smem;
  float*  stage = (float*)smem;
  __shared__ float wlds[NFILT * CH];
  const int chalf = blockIdx.x;
  const int col   = blockIdx.y;
  const int n = col >> 8, w = col & 255;
  const int c0 = chalf * CH;
  const int t = threadIdx.x;
  const int wave = t >> 6, lane = t & 63;

  if (t < CH) {
    const int c = c0 + t;
    float g0 = gate[0 * C_ + c], g1 = gate[1 * C_ + c];
    float g2 = gate[2 * C_ + c], g3 = gate[3 * C_ + c];
    float mx = fmaxf(fmaxf(g0, g1), fmaxf(g2, g3));
    float e0 = __expf(g0 - mx), e1 = __expf(g1 - mx);
    float e2 = __expf(g2 - mx), e3 = __expf(g3 - mx);
    float inv = 1.0f / (e0 + e1 + e2 + e3);
    wlds[0 * CH + t] = e0 * inv;
    wlds[1 * CH + t] = e1 * inv;
    wlds[2 * CH + t] = e2 * inv;
    wlds[3 * CH + t] = e3 * inv;
  }

  float acc[NFR][4];
  #pragma unroll
  for (int ci = 0; ci < NFR; ++ci)
    acc[ci][0] = acc[ci][1] = acc[ci][2] = acc[ci][3] = 0.0f;

  const size_t chunk = (size_t)H_ * CH;
  uint4 pf[6];
  {
    const uint4* src = (const uint4*)(inter +
        ((size_t)(0 * 2 + chalf) * N_ * W_ + (size_t)n * W_ + w) * chunk);
    #pragma unroll
    for (int i = 0; i < 6; ++i) pf[i] = src[i * 256 + t];
  }

  for (int fi = 0; fi < nf; ++fi) {
    __syncthreads();
    #pragma unroll
    for (int i = 0; i < 6; ++i) {
      int e = i * 256 + t;
      int hh = e / 6, c8 = e % 6;
      union { uint4 u4; ushort sv[8]; } pk;
      pk.u4 = pf[i];
      #pragma unroll
      for (int k = 0; k < 8; ++k)
        tile[(8 * c8 + k) * TP + hh] = __ushort_as_half(pk.sv[k]);
    }
    __syncthreads();
    if (fi + 1 < nf) {
      const uint4* src = (const uint4*)(inter +
          ((size_t)((fi + 1) * 2 + chalf) * N_ * W_ + (size_t)n * W_ + w) * chunk);
      #pragma unroll
      for (int i = 0; i < 6; ++i) pf[i] = src[i * 256 + t];
    }
    const float a = c_a[f_start + fi];
    #pragma unroll
    for (int ci = 0; ci < NFR; ++ci) {
      const int c = wave + 4 * ci;
      const __half2* p = (const __half2*)(tile + c * TP + 4 * lane);
      float2 f01 = __half22float2(p[0]);
      float2 f23 = __half22float2(p[1]);
      float v0 = f01.x, v1 = f01.y, v2 = f23.x, v3 = f23.y;
      scan_fwd(v0, v1, v2, v3, a, lane);
      scan_bwd(v0, v1, v2, v3, a, lane);
      const float wg = wlds[(f_start + fi) * CH + c];
      acc[ci][0] = fmaf(wg, v0, acc[ci][0]);
      acc[ci][1] = fmaf(wg, v1, acc[ci][1]);
      acc[ci][2] = fmaf(wg, v2, acc[ci][2]);
      acc[ci][3] = fmaf(wg, v3, acc[ci][3]);
    }
  }

  #pragma unroll
  for (int r = 0; r < 2; ++r) {
    __syncthreads();
    if ((lane >> 5) == r) {
      const int hl = 4 * (lane & 31);
      #pragma unroll
      for (int ci = 0; ci < NFR; ++ci) {
        float4* sp = (float4*)(stage + (wave + 4 * ci) * SP + hl);
        *sp = make_float4(acc[ci][0], acc[ci][1], acc[ci][2], acc[ci][3]);
      }
    }
    __syncthreads();
    float* obase = out + (((size_t)n * H_ + 128 * r) * W_ + w) * C_ + c0;
    #pragma unroll
    for (int i = 0; i < 6; ++i) {
      int idx = t + i * 256;
      int hl = idx / 12, c4 = idx % 12;
      float4 v;
      v.x = stage[(4 * c4 + 0) * SP + hl];
      v.y = stage[(4 * c4 + 1) * SP + hl];
      v.z = stage[(4 * c4 + 2) * SP + hl];
      v.w = stage[(4 * c4 + 3) * SP + hl];
      float4* dst = (float4*)(obase + (size_t)hl * (W_ * C_) + 4 * c4);
      if (accumulate) {
        float4 pv = *dst;
        v.x += pv.x; v.y += pv.y; v.z += pv.z; v.w += pv.w;
      }
      *dst = v;
    }
  }
}

extern "C" void kernel_launch(void* const* d_in, const int* in_sizes, int n_in,
                              void* d_out, int out_size, void* d_ws, size_t ws_size,
                              hipStream_t stream) {
  const float* x    = (const float*)d_in[0];
  const float* gate = (const float*)d_in[1];
  float* out        = (float*)d_out;
  __half* inter     = (__half*)d_ws;

  const size_t per_f = (size_t)N_ * H_ * W_ * C_ * sizeof(__half);  // 50.3 MB
  int batch = 1;
  if (ws_size >= 4 * per_f)      batch = 4;
  else if (ws_size >= 2 * per_f) batch = 2;

  int done = 0;
  while (done < NFILT) {
    int nf = NFILT - done;
    if (nf > batch) nf = batch;
    if (nf == 4) {
      k_wpass4<<<dim3(8192), dim3(256), 0, stream>>>(x, inter);
    } else {
      dim3 g1(2 * nf, N_ * H_);
      k_wpass<<<g1, dim3(256), 0, stream>>>(x, inter, done, nf);
    }
    dim3 g2(2, N_ * W_);
    k_hpass<<<g2, dim3(256), 0, stream>>>(inter, gate, out, done, nf,
                                          done > 0 ? 1 : 0);
    done += nf;
  }
}